// Round 1
// baseline (198.363 us; speedup 1.0000x reference)
//
#include <hip/hip_runtime.h>

#define B_ 16
#define C_ 64
#define N_ 16384          // 128*128
#define GSLICES 64        // gram: N-slices per batch -> 16*64 = 1024 blocks
#define TILE_COLS 64      // gram: columns staged per LDS tile
#define NSLICE 64         // out: columns per block

// -------- zero the gram scratch (atomic accumulation target) --------
__global__ void zero_ws_kernel(float* __restrict__ p, int n) {
    int i = blockIdx.x * blockDim.x + threadIdx.x;
    if (i < n) p[i] = 0.f;
}

// -------- pass 1: partial gram G_b = X_b X_b^T (unnormalized) --------
// block = (batch b, slice s of 256 columns). 256 threads = 4 waves.
// wave q handles 16 of the 64 staged columns; lane g owns the 8x8 gram
// subtile (c0,d0) = ((g>>3)*8, (g&7)*8). LDS tile is stored transposed
// ldsT[col][chan] so fragment reads are contiguous float4s.
__global__ __launch_bounds__(256, 4)
void gram_kernel(const float* __restrict__ x, float* __restrict__ gram) {
    __shared__ float ldsT[TILE_COLS][C_ + 4];  // stride 68 floats = 272B (16B aligned)
    __shared__ float gsum[C_][C_];             // XOR-swizzled accumulation buffer

    const int t = threadIdx.x;
    const int b = blockIdx.y, s = blockIdx.x;
    const float* xb = x + (size_t)b * C_ * N_;
    const int g = t & 63, q = t >> 6;
    const int c0 = (g >> 3) << 3, d0 = (g & 7) << 3;
    const int gc = g >> 3;  // swizzle key = c0>>3

    // zero the block-level gram accumulator (visible after first __syncthreads)
    for (int i = t; i < C_ * C_; i += 256) (&gsum[0][0])[i] = 0.f;

    float acc[8][8];
    #pragma unroll
    for (int i = 0; i < 8; ++i)
        #pragma unroll
        for (int j = 0; j < 8; ++j) acc[i][j] = 0.f;

    const int cols_per_block = N_ / GSLICES;     // 256
    const int n_base = s * cols_per_block;
    const int cstage = t >> 2, jstage = (t & 3) * 16;

    for (int tile = 0; tile < cols_per_block / TILE_COLS; ++tile) {
        const int n0 = n_base + tile * TILE_COLS;
        // stage 64 cols x 64 chans, transposed into LDS
        const float* src = xb + (size_t)cstage * N_ + n0 + jstage;
        #pragma unroll
        for (int k = 0; k < 4; ++k) {
            float4 v = ((const float4*)src)[k];
            ldsT[jstage + 4 * k + 0][cstage] = v.x;
            ldsT[jstage + 4 * k + 1][cstage] = v.y;
            ldsT[jstage + 4 * k + 2][cstage] = v.z;
            ldsT[jstage + 4 * k + 3][cstage] = v.w;
        }
        __syncthreads();
        // rank-16 update of the 8x8 subtile
        #pragma unroll
        for (int i = 0; i < 16; ++i) {
            const float* row = &ldsT[q * 16 + i][0];
            float4 a0 = *(const float4*)(row + c0);
            float4 a1 = *(const float4*)(row + c0 + 4);
            float4 b0 = *(const float4*)(row + d0);
            float4 b1 = *(const float4*)(row + d0 + 4);
            float av[8] = {a0.x, a0.y, a0.z, a0.w, a1.x, a1.y, a1.z, a1.w};
            float bv[8] = {b0.x, b0.y, b0.z, b0.w, b1.x, b1.y, b1.z, b1.w};
            #pragma unroll
            for (int ci = 0; ci < 8; ++ci)
                #pragma unroll
                for (int dj = 0; dj < 8; ++dj)
                    acc[ci][dj] = fmaf(av[ci], bv[dj], acc[ci][dj]);
        }
        __syncthreads();
    }

    // block-level reduce: LDS float atomics, XOR-swizzled so a wave's 64
    // lanes land 2 addresses/bank (free). Then one global atomicAdd per entry.
    #pragma unroll
    for (int ci = 0; ci < 8; ++ci)
        #pragma unroll
        for (int dj = 0; dj < 8; ++dj)
            atomicAdd(&gsum[c0 + ci][(d0 + dj) ^ gc], acc[ci][dj]);
    __syncthreads();

    float* gb = gram + (size_t)b * C_ * C_;
    for (int i = t; i < C_ * C_; i += 256) {
        int cc = i >> 6, dd = i & 63;
        atomicAdd(&gb[i], gsum[cc][dd ^ (cc >> 3)]);
    }
}

// -------- pass 2 (tiny): Mt[b][d][o] = (1/N) * sum_c W[o][c] G_b[c][d] --------
__global__ void m_kernel(const float* __restrict__ W, const float* __restrict__ gram,
                         float* __restrict__ Mt) {
    __shared__ float Gs[C_][C_ + 1];
    __shared__ float Ws[C_][C_ + 1];
    const int b = blockIdx.x, t = threadIdx.x;
    const float* gb = gram + (size_t)b * C_ * C_;
    for (int i = t; i < C_ * C_; i += 256) {
        Gs[i >> 6][i & 63] = gb[i];
        Ws[i >> 6][i & 63] = W[i];
    }
    __syncthreads();
    const int o = t & 63, dg = t >> 6;
    const float invN = 1.0f / (float)N_;
    #pragma unroll
    for (int dk = 0; dk < 16; ++dk) {
        const int d = dg * 16 + dk;
        float sum = 0.f;
        #pragma unroll
        for (int c = 0; c < C_; ++c) sum = fmaf(Ws[o][c], Gs[c][d], sum);
        Mt[((size_t)b * C_ + d) * C_ + o] = sum * invN;
    }
}

// -------- pass 3: out_b = M_b @ X_b --------
// block = (batch b, 64-column slice). Stage M_b (as Mt[d][o]) and the x
// slice in LDS; thread computes a 4(o) x 4(n) register tile.
__global__ __launch_bounds__(256, 4)
void out_kernel(const float* __restrict__ x, const float* __restrict__ Mt,
                float* __restrict__ out) {
    __shared__ float Ms[C_][C_ + 4];       // Ms[d][o]
    __shared__ float Xs[C_][NSLICE + 4];   // Xs[d][n]
    const int t = threadIdx.x;
    const int b = blockIdx.y;
    const int n0 = blockIdx.x * NSLICE;
    const float* xb = x + (size_t)b * C_ * N_;

    const int dstage = t >> 2, jstage = (t & 3) * 16;
    {
        const float4* srcm = (const float4*)(Mt + ((size_t)b * C_ + dstage) * C_ + jstage);
        float4* dstm = (float4*)(&Ms[dstage][jstage]);
        const float4* srcx = (const float4*)(xb + (size_t)dstage * N_ + n0 + jstage);
        float4* dstx = (float4*)(&Xs[dstage][jstage]);
        #pragma unroll
        for (int k = 0; k < 4; ++k) { dstm[k] = srcm[k]; dstx[k] = srcx[k]; }
    }
    __syncthreads();

    const int o0 = (t >> 4) * 4, nc = (t & 15) * 4;
    float acc[4][4] = {{0.f,0.f,0.f,0.f},{0.f,0.f,0.f,0.f},
                       {0.f,0.f,0.f,0.f},{0.f,0.f,0.f,0.f}};
    #pragma unroll
    for (int d = 0; d < C_; ++d) {
        float4 m4 = *(const float4*)(&Ms[d][o0]);
        float4 x4 = *(const float4*)(&Xs[d][nc]);
        float mv[4] = {m4.x, m4.y, m4.z, m4.w};
        float xv[4] = {x4.x, x4.y, x4.z, x4.w};
        #pragma unroll
        for (int oi = 0; oi < 4; ++oi)
            #pragma unroll
            for (int nj = 0; nj < 4; ++nj)
                acc[oi][nj] = fmaf(mv[oi], xv[nj], acc[oi][nj]);
    }

    float* ob = out + (size_t)b * C_ * N_;
    #pragma unroll
    for (int oi = 0; oi < 4; ++oi) {
        float4 v = make_float4(acc[oi][0], acc[oi][1], acc[oi][2], acc[oi][3]);
        *(float4*)(ob + (size_t)(o0 + oi) * N_ + n0 + nc) = v;
    }
}

extern "C" void kernel_launch(void* const* d_in, const int* in_sizes, int n_in,
                              void* d_out, int out_size, void* d_ws, size_t ws_size,
                              hipStream_t stream) {
    const float* x = (const float*)d_in[0];   // [16,64,128,128]
    const float* w = (const float*)d_in[1];   // [64,64]
    float* out = (float*)d_out;               // [16,64,128,128]
    float* gram = (float*)d_ws;               // 16*64*64 floats
    float* Mt = gram + B_ * C_ * C_;          // 16*64*64 floats

    zero_ws_kernel<<<dim3((B_ * C_ * C_ + 255) / 256), 256, 0, stream>>>(gram, B_ * C_ * C_);
    gram_kernel<<<dim3(GSLICES, B_), 256, 0, stream>>>(x, gram);
    m_kernel<<<dim3(B_), 256, 0, stream>>>(w, gram, Mt);
    out_kernel<<<dim3(N_ / NSLICE, B_), 256, 0, stream>>>(x, Mt, out);
}

// Round 2
// 66.346 us; speedup vs baseline: 2.9898x; 2.9898x over previous
//
#include <hip/hip_runtime.h>

#define B_ 16
#define C_ 64
#define N_ 16384          // 128*128
#define KCHUNKS 32        // gram k-chunks -> 16*32 = 512 blocks
#define NW 256            // out: columns per block
#define SROW 72           // Xt row stride in bf16 (pad 64 -> 72, 16B-aligned rows)

typedef __attribute__((ext_vector_type(8))) short bf16x8;
typedef __attribute__((ext_vector_type(4))) float f32x4;

// fp32 -> bf16 round-to-nearest-even, bit form
__device__ __forceinline__ unsigned short f2bf(float f) {
    unsigned int u = __float_as_uint(f);
    unsigned int r = (u + 0x7FFFu + ((u >> 16) & 1u)) >> 16;
    return (unsigned short)r;
}

__device__ __forceinline__ bf16x8 cvt8(float4 lo, float4 hi) {
    bf16x8 r;
    r[0] = (short)f2bf(lo.x); r[1] = (short)f2bf(lo.y);
    r[2] = (short)f2bf(lo.z); r[3] = (short)f2bf(lo.w);
    r[4] = (short)f2bf(hi.x); r[5] = (short)f2bf(hi.y);
    r[6] = (short)f2bf(hi.z); r[7] = (short)f2bf(hi.w);
    return r;
}

// -------- pass 1: per-(batch, k-chunk) partial gram via bf16 MFMA --------
// 4 waves/block; wave w owns 128 columns (4 k-steps of 32). Each wave
// computes the FULL 64x64 gram partial: fragments loaded straight from
// global (row-major X == fragment layout since gram contracts the fast dim),
// one fragment serves as both A (c-rows) and B (d-cols). No atomics:
// block-reduce in LDS, then coalesced store of the block partial.
__global__ __launch_bounds__(256)
void gram_kernel(const float* __restrict__ x, float* __restrict__ gpart) {
    __shared__ float red[4][4096];   // 64 KiB: [wave][tile*256 + lane*4 + reg]
    const int t = threadIdx.x, l = t & 63, w = t >> 6;
    const int b = blockIdx.y, ch = blockIdx.x;
    const float* xb = x + (size_t)b * (C_ * (size_t)N_);
    const int row = l & 15, kg = l >> 4;

    f32x4 acc[4][4] = {};

    const int kbase = ch * (N_ / KCHUNKS) + w * 128;
    for (int ks = 0; ks < 4; ++ks) {
        const int k0 = kbase + ks * 32 + kg * 8;
        bf16x8 frag[4];
        #pragma unroll
        for (int g = 0; g < 4; ++g) {
            const float* p = xb + (size_t)(16 * g + row) * N_ + k0;
            float4 lo = *(const float4*)p;
            float4 hi = *(const float4*)(p + 4);
            frag[g] = cvt8(lo, hi);
        }
        #pragma unroll
        for (int gc = 0; gc < 4; ++gc)
            #pragma unroll
            for (int gd = 0; gd < 4; ++gd)
                acc[gc][gd] = __builtin_amdgcn_mfma_f32_16x16x32_bf16(
                    frag[gc], frag[gd], acc[gc][gd], 0, 0, 0);
    }

    #pragma unroll
    for (int gc = 0; gc < 4; ++gc)
        #pragma unroll
        for (int gd = 0; gd < 4; ++gd) {
            const int tile = gc * 4 + gd;
            *(f32x4*)&red[w][tile * 256 + l * 4] = acc[gc][gd];
        }
    __syncthreads();

    float* dst = gpart + (size_t)(b * KCHUNKS + ch) * 4096;
    for (int i = t; i < 4096; i += 256)
        dst[i] = red[0][i] + red[1][i] + red[2][i] + red[3][i];
}

// -------- pass 2 (tiny): reduce partials, decode C-layout, apply W, emit bf16 M --------
// M[o][d] = (1/N) * sum_c W[o][c] G[c][d], stored row-major bf16 (A-frag-ready).
__global__ __launch_bounds__(256)
void m_kernel(const float* __restrict__ W, const float* __restrict__ gpart,
              unsigned short* __restrict__ Mbf) {
    __shared__ float Gs[C_][C_ + 1];
    __shared__ float Ws[C_][C_ + 1];
    const int b = blockIdx.x, t = threadIdx.x;

    for (int i = t; i < 4096; i += 256) {
        float s = 0.f;
        const float* p = gpart + (size_t)b * KCHUNKS * 4096 + i;
        for (int ch = 0; ch < KCHUNKS; ++ch) s += p[(size_t)ch * 4096];
        // decode red-layout index -> (c,d): D row = 4*(lane>>4)+reg, col = lane&15
        const int tile = i >> 8, li = (i >> 2) & 63, r = i & 3;
        const int gc = tile >> 2, gd = tile & 3;
        const int c = gc * 16 + (li >> 4) * 4 + r;
        const int d = gd * 16 + (li & 15);
        Gs[c][d] = s;
    }
    for (int i = t; i < 4096; i += 256) Ws[i >> 6][i & 63] = W[i];
    __syncthreads();

    const int o = t & 63, dg = t >> 6;
    const float invN = 1.0f / (float)N_;
    #pragma unroll
    for (int dk = 0; dk < 16; ++dk) {
        const int d = dg * 16 + dk;
        float s = 0.f;
        #pragma unroll
        for (int c = 0; c < C_; ++c) s = fmaf(Ws[o][c], Gs[c][d], s);
        Mbf[((size_t)b * C_ + o) * C_ + d] = f2bf(s * invN);
    }
}

// -------- pass 3: out_b = M_b @ X_b via bf16 MFMA --------
// A = M (o-rows), loaded as fragments straight from global (tiny, L3-hot).
// B = X needs the slow dim as K -> stage a transposed bf16 tile Xt[n][d] in
// LDS (pad to 72 so fragment reads spread banks). 2 k-steps cover d=0..63.
__global__ __launch_bounds__(256)
void out_kernel(const float* __restrict__ x, const unsigned short* __restrict__ Mbf,
                float* __restrict__ out) {
    __shared__ unsigned short Xt[NW][SROW];   // 36 KiB
    const int t = threadIdx.x, l = t & 63, w = t >> 6;
    const int b = blockIdx.y, n0 = blockIdx.x * NW;
    const float* xb = x + (size_t)b * (C_ * (size_t)N_);
    const int row = l & 15, kg = l >> 4;

    // A fragments: lane l -> M[16g+row][ks*32 + kg*8 + j]
    bf16x8 afrag[2][4];
    #pragma unroll
    for (int ks = 0; ks < 2; ++ks)
        #pragma unroll
        for (int g = 0; g < 4; ++g)
            afrag[ks][g] = *(const bf16x8*)(Mbf +
                ((size_t)b * C_ + 16 * g + row) * C_ + ks * 32 + kg * 8);

    // stage+transpose: thread t -> d = t>>2, n-quarter = (t&3)*64
    const int d = t >> 2, nq = (t & 3) * 64;
    #pragma unroll
    for (int i = 0; i < 16; ++i) {
        float4 v = *(const float4*)(xb + (size_t)d * N_ + n0 + nq + 4 * i);
        Xt[nq + 4 * i + 0][d] = f2bf(v.x);
        Xt[nq + 4 * i + 1][d] = f2bf(v.y);
        Xt[nq + 4 * i + 2][d] = f2bf(v.z);
        Xt[nq + 4 * i + 3][d] = f2bf(v.w);
    }
    __syncthreads();

    float* ob = out + (size_t)b * (C_ * (size_t)N_);
    #pragma unroll
    for (int nt = 0; nt < 4; ++nt) {
        const int ntile = w * 4 + nt;
        bf16x8 bfrag0 = *(const bf16x8*)&Xt[ntile * 16 + row][kg * 8];
        bf16x8 bfrag1 = *(const bf16x8*)&Xt[ntile * 16 + row][32 + kg * 8];
        #pragma unroll
        for (int g = 0; g < 4; ++g) {
            f32x4 acc = {};
            acc = __builtin_amdgcn_mfma_f32_16x16x32_bf16(afrag[0][g], bfrag0, acc, 0, 0, 0);
            acc = __builtin_amdgcn_mfma_f32_16x16x32_bf16(afrag[1][g], bfrag1, acc, 0, 0, 0);
            // D: row(o) = 4*kg + r within tile g, col(n) = row(lane&15)
            #pragma unroll
            for (int r = 0; r < 4; ++r)
                ob[(size_t)(16 * g + 4 * kg + r) * N_ + n0 + ntile * 16 + row] = acc[r];
        }
    }
}

extern "C" void kernel_launch(void* const* d_in, const int* in_sizes, int n_in,
                              void* d_out, int out_size, void* d_ws, size_t ws_size,
                              hipStream_t stream) {
    const float* x = (const float*)d_in[0];   // [16,64,128,128] fp32
    const float* w = (const float*)d_in[1];   // [64,64] fp32
    float* out = (float*)d_out;               // [16,64,128,128] fp32
    float* gpart = (float*)d_ws;                              // 16*32*4096 f32 = 8 MiB
    unsigned short* Mbf = (unsigned short*)((char*)d_ws + (size_t)B_ * KCHUNKS * 4096 * 4);

    gram_kernel<<<dim3(KCHUNKS, B_), 256, 0, stream>>>(x, gpart);
    m_kernel<<<dim3(B_), 256, 0, stream>>>(w, gpart, Mbf);
    out_kernel<<<dim3(N_ / NW, B_), 256, 0, stream>>>(x, Mbf, out);
}